// Round 5
// baseline (586.784 us; speedup 1.0000x reference)
//
#include <hip/hip_runtime.h>
#include <hip/hip_bf16.h>
#include <cstdint>

typedef short short8 __attribute__((ext_vector_type(8)));
typedef __bf16 bf16x8 __attribute__((ext_vector_type(8)));
typedef float float4v __attribute__((ext_vector_type(4)));
typedef float float16v __attribute__((ext_vector_type(16)));

#define NKV 8
#define G 8
#define D 64
#define NH 64
#define BB 2
#define S 1024
#define H 4096
#define MROWS (BB*S)         // 2048
#define NQKV (H + 2*NKV*D)   // 5120

__device__ __forceinline__ unsigned short f2b(float f) {
    union { float f; uint32_t u; } v; v.f = f;
    uint32_t u = v.u;
    uint32_t r = (u + 0x7FFFu + ((u >> 16) & 1u)) >> 16;
    return (unsigned short)r;
}
__device__ __forceinline__ float b2f(unsigned short b) {
    union { float f; uint32_t u; } v; v.u = ((uint32_t)b) << 16;
    return v.f;
}

__device__ __forceinline__ void gload_lds16(const unsigned short* g, unsigned short* l) {
    __builtin_amdgcn_global_load_lds(
        (const __attribute__((address_space(1))) uint32_t*)g,
        (__attribute__((address_space(3))) uint32_t*)l, 16, 0, 0);
}

// ---------------- fused fp32 -> bf16 conversion for all 5 tensors ----------------
__global__ void cvt_all(const float* __restrict__ hs, const float* __restrict__ wq,
                        const float* __restrict__ wk, const float* __restrict__ wv,
                        const float* __restrict__ wd,
                        unsigned short* __restrict__ hs_b, unsigned short* __restrict__ wqkv_b,
                        unsigned short* __restrict__ wd_b) {
    const size_t N0 = (size_t)MROWS * H;
    const size_t N1 = (size_t)H * H;
    const size_t N2 = (size_t)512 * H;
    const size_t N3 = (size_t)512 * H;
    const size_t N4 = (size_t)H * H;
    const size_t total4 = (N0 + N1 + N2 + N3 + N4) / 4;
    size_t i = (size_t)blockIdx.x * blockDim.x + threadIdx.x;
    const size_t stride = (size_t)gridDim.x * blockDim.x;
    for (; i < total4; i += stride) {
        size_t e = i * 4;
        const float* s; unsigned short* d;
        if (e < N0)                { s = hs + e;                  d = hs_b + e; }
        else if (e < N0+N1)        { s = wq + (e-N0);             d = wqkv_b + (e-N0); }
        else if (e < N0+N1+N2)     { s = wk + (e-N0-N1);          d = wqkv_b + N1 + (e-N0-N1); }
        else if (e < N0+N1+N2+N3)  { s = wv + (e-N0-N1-N2);       d = wqkv_b + N1+N2 + (e-N0-N1-N2); }
        else                       { s = wd + (e-N0-N1-N2-N3);    d = wd_b + (e-N0-N1-N2-N3); }
        float4 f = *(const float4*)s;
        ushort4 o;
        o.x = f2b(f.x); o.y = f2b(f.y); o.z = f2b(f.z); o.w = f2b(f.w);
        *(ushort4*)d = o;
    }
}

// ---------------- GEMM1 with fused RoPE + head-scatter epilogue ----------------
// C[2048,5120] = hs_b * wqkv_b^T, then per-region epilogue:
//   cols [0,4096): Q + RoPE -> qa[h][s][d];  [4096,4608): K + RoPE -> ka;
//   [4608,5120): V -> vt (transposed [d][s]).
// acc[mg][0]/acc[mg][1] hold d and d+32 of a 64-aligned head slice at the same
// reg/lane -> rotate-half pairing is register-local.
__global__ __launch_bounds__(256) void gemm_qkv(
    const unsigned short* __restrict__ A, const unsigned short* __restrict__ W,
    const float* __restrict__ cosb, const float* __restrict__ sinb,
    unsigned short* __restrict__ qa, unsigned short* __restrict__ ka,
    unsigned short* __restrict__ vt) {
    const int K = H;
    __shared__ unsigned short As[128 * 32];
    __shared__ unsigned short Bs[128 * 32];
    const int bm = blockIdx.y * 128, bn = blockIdx.x * 128;
    const int tid = threadIdx.x;
    const int w = tid >> 6, lane = tid & 63;
    const int n32 = lane & 31, khalf = lane >> 5;
    const int wm = (w & 1) * 64, wn = (w >> 1) * 64;

    const int r0 = tid >> 2;
    const int c0 = (tid & 3) ^ ((r0 >> 2) & 3);
    const unsigned short* pA0 = A + (size_t)(bm + r0) * K + c0 * 8;
    const unsigned short* pA1 = A + (size_t)(bm + r0 + 64) * K + c0 * 8;
    const unsigned short* pW0 = W + (size_t)(bn + r0) * K + c0 * 8;
    const unsigned short* pW1 = W + (size_t)(bn + r0 + 64) * K + c0 * 8;
    unsigned short* Asl0 = As + tid * 8;
    unsigned short* Asl1 = As + 2048 + tid * 8;
    unsigned short* Bsl0 = Bs + tid * 8;
    unsigned short* Bsl1 = Bs + 2048 + tid * 8;

    const unsigned short* aP[2][2];
    const unsigned short* bP[2][2];
#pragma unroll
    for (int g = 0; g < 2; g++)
#pragma unroll
        for (int s = 0; s < 2; s++) {
            int cp = ((s << 1) | khalf) ^ ((n32 >> 2) & 3);
            aP[g][s] = &As[(wm + g * 32 + n32) * 32 + cp * 8];
            bP[g][s] = &Bs[(wn + g * 32 + n32) * 32 + cp * 8];
        }

    float16v acc[2][2] = {};
    const int iters = K >> 5;
    for (int it = 0; it < iters; ++it) {
        __syncthreads();
        gload_lds16(pA0, Asl0);
        gload_lds16(pA1, Asl1);
        gload_lds16(pW0, Bsl0);
        gload_lds16(pW1, Bsl1);
        pA0 += 32; pA1 += 32; pW0 += 32; pW1 += 32;
        __syncthreads();
        bf16x8 af[2][2], bf[2][2];
#pragma unroll
        for (int g = 0; g < 2; g++)
#pragma unroll
            for (int s = 0; s < 2; s++) {
                af[g][s] = *(const bf16x8*)aP[g][s];
                bf[g][s] = *(const bf16x8*)bP[g][s];
            }
#pragma unroll
        for (int s = 0; s < 2; s++)
#pragma unroll
            for (int mg = 0; mg < 2; mg++)
#pragma unroll
                for (int ng = 0; ng < 2; ng++)
                    acc[mg][ng] = __builtin_amdgcn_mfma_f32_32x32x16_bf16(
                        af[mg][s], bf[ng][s], acc[mg][ng], 0, 0, 0);
    }

    // epilogue — base = 64-aligned output-feature block this wave owns
    const int base = bn + wn;
    if (base < H) {
        const int hloc = base >> 6;   // head within batch
#pragma unroll
        for (int mg = 0; mg < 2; mg++) {
#pragma unroll
            for (int reg = 0; reg < 16; reg++) {
                int grow = bm + wm + mg * 32 + (reg & 3) + 8 * (reg >> 2) + 4 * khalf;
                int s = grow & 1023, b = grow >> 10;
                float c0 = cosb[s * 64 + n32],      s0 = sinb[s * 64 + n32];
                float c1 = cosb[s * 64 + 32 + n32], s1 = sinb[s * 64 + 32 + n32];
                float x0 = acc[mg][0][reg], x1 = acc[mg][1][reg];
                size_t off = ((size_t)(b * 64 + hloc) * S + s) * 64;
                qa[off + n32]      = f2b(x0 * c0 - x1 * s0);
                qa[off + 32 + n32] = f2b(x1 * c1 + x0 * s1);
            }
        }
    } else if (base < H + 512) {
        const int kvh = (base - H) >> 6;
#pragma unroll
        for (int mg = 0; mg < 2; mg++) {
#pragma unroll
            for (int reg = 0; reg < 16; reg++) {
                int grow = bm + wm + mg * 32 + (reg & 3) + 8 * (reg >> 2) + 4 * khalf;
                int s = grow & 1023, b = grow >> 10;
                float c0 = cosb[s * 64 + n32],      s0 = sinb[s * 64 + n32];
                float c1 = cosb[s * 64 + 32 + n32], s1 = sinb[s * 64 + 32 + n32];
                float x0 = acc[mg][0][reg], x1 = acc[mg][1][reg];
                size_t off = ((size_t)(b * NKV + kvh) * S + s) * 64;
                ka[off + n32]      = f2b(x0 * c0 - x1 * s0);
                ka[off + 32 + n32] = f2b(x1 * c1 + x0 * s1);
            }
        }
    } else {
        const int kvh = (base - H - 512) >> 6;
#pragma unroll
        for (int mg = 0; mg < 2; mg++) {
#pragma unroll
            for (int reg = 0; reg < 16; reg++) {
                int grow = bm + wm + mg * 32 + (reg & 3) + 8 * (reg >> 2) + 4 * khalf;
                int s = grow & 1023, b = grow >> 10;
                size_t hb = (size_t)(b * NKV + kvh) * 64;
                vt[(hb + n32) * S + s]      = f2b(acc[mg][0][reg]);
                vt[(hb + 32 + n32) * S + s] = f2b(acc[mg][1][reg]);
            }
        }
    }
}

// ---------------- generic NT GEMM (fp32 out) for the output projection ----------------
__global__ __launch_bounds__(256) void gemm_nt_f32(
    const unsigned short* __restrict__ A, const unsigned short* __restrict__ W,
    float* __restrict__ C, int M, int N, int K) {
    __shared__ unsigned short As[128 * 32];
    __shared__ unsigned short Bs[128 * 32];
    const int bm = blockIdx.y * 128, bn = blockIdx.x * 128;
    const int tid = threadIdx.x;
    const int w = tid >> 6, lane = tid & 63;
    const int n32 = lane & 31, khalf = lane >> 5;
    const int wm = (w & 1) * 64, wn = (w >> 1) * 64;

    const int r0 = tid >> 2;
    const int c0 = (tid & 3) ^ ((r0 >> 2) & 3);
    const unsigned short* pA0 = A + (size_t)(bm + r0) * K + c0 * 8;
    const unsigned short* pA1 = A + (size_t)(bm + r0 + 64) * K + c0 * 8;
    const unsigned short* pW0 = W + (size_t)(bn + r0) * K + c0 * 8;
    const unsigned short* pW1 = W + (size_t)(bn + r0 + 64) * K + c0 * 8;
    unsigned short* Asl0 = As + tid * 8;
    unsigned short* Asl1 = As + 2048 + tid * 8;
    unsigned short* Bsl0 = Bs + tid * 8;
    unsigned short* Bsl1 = Bs + 2048 + tid * 8;

    const unsigned short* aP[2][2];
    const unsigned short* bP[2][2];
#pragma unroll
    for (int g = 0; g < 2; g++)
#pragma unroll
        for (int s = 0; s < 2; s++) {
            int cp = ((s << 1) | khalf) ^ ((n32 >> 2) & 3);
            aP[g][s] = &As[(wm + g * 32 + n32) * 32 + cp * 8];
            bP[g][s] = &Bs[(wn + g * 32 + n32) * 32 + cp * 8];
        }

    float16v acc[2][2] = {};
    const int iters = K >> 5;
    for (int it = 0; it < iters; ++it) {
        __syncthreads();
        gload_lds16(pA0, Asl0);
        gload_lds16(pA1, Asl1);
        gload_lds16(pW0, Bsl0);
        gload_lds16(pW1, Bsl1);
        pA0 += 32; pA1 += 32; pW0 += 32; pW1 += 32;
        __syncthreads();
        bf16x8 af[2][2], bf[2][2];
#pragma unroll
        for (int g = 0; g < 2; g++)
#pragma unroll
            for (int s = 0; s < 2; s++) {
                af[g][s] = *(const bf16x8*)aP[g][s];
                bf[g][s] = *(const bf16x8*)bP[g][s];
            }
#pragma unroll
        for (int s = 0; s < 2; s++)
#pragma unroll
            for (int mg = 0; mg < 2; mg++)
#pragma unroll
                for (int ng = 0; ng < 2; ng++)
                    acc[mg][ng] = __builtin_amdgcn_mfma_f32_32x32x16_bf16(
                        af[mg][s], bf[ng][s], acc[mg][ng], 0, 0, 0);
    }
#pragma unroll
    for (int mg = 0; mg < 2; mg++)
#pragma unroll
        for (int ng = 0; ng < 2; ng++) {
            int gcol = bn + wn + ng * 32 + n32;
#pragma unroll
            for (int reg = 0; reg < 16; reg++) {
                int grow = bm + wm + mg * 32 + (reg & 3) + 8 * (reg >> 2) + 4 * khalf;
                C[(size_t)grow * N + gcol] = acc[mg][ng][reg];
            }
        }
}

// ---------------- Flash attention: 32x32 MFMA, 128-row Q tiles, pair-balanced ----------------
// blockIdx.x = pair p (0..3): Q tiles qt=p and 7-p -> 18 staged K-tiles/block.
// blockIdx.y = head (0..127). Wave w owns q rows [qb+32w, qb+32w+32).
// Wave-uniform skip of K-tiles fully above the wave's diagonal (kb > wbase):
// guarantees no fully-masked row (kb <= wbase -> key kb valid for every row).
__global__ __launch_bounds__(256) void attn_kernel(
    const unsigned short* __restrict__ qa, const unsigned short* __restrict__ ka,
    const unsigned short* __restrict__ vt, unsigned short* __restrict__ out) {
    __shared__ unsigned short Ks[64 * 72];   // [key][d]
    __shared__ unsigned short Vs[64 * 72];   // [d][key]  (V^T)
    __shared__ unsigned short Ps[4 * 32 * 72]; // per-wave [q][key]
    const int p = blockIdx.x;
    const int h = blockIdx.y;
    const int b = h >> 6, kvh = (h >> 3) & 7;
    const int tid = threadIdx.x, w = tid >> 6, lane = tid & 63;
    const int n32 = lane & 31, khalf = lane >> 5;
    const unsigned short* Kg = ka + (size_t)(b * NKV + kvh) * (S * D);
    const unsigned short* Vg = vt + (size_t)(b * NKV + kvh) * (D * S);
    const int srow = tid >> 3, scc = (tid & 7) * 8;
    const float SC2 = 0.125f * 1.44269504089f;   // 1/sqrt(D) * log2(e)
    unsigned short* Pw = Ps + w * 32 * 72;

#pragma unroll
    for (int part = 0; part < 2; part++) {
        const int qt = part ? (7 - p) : p;
        const int qb = qt * 128;
        const int wbase = qb + w * 32;

        bf16x8 aq[4];
#pragma unroll
        for (int kst = 0; kst < 4; kst++)
            aq[kst] = *(const bf16x8*)&qa[(size_t)h * (S * D)
                                          + (size_t)(wbase + n32) * 64 + kst * 16 + khalf * 8];

        float m_run[16], l_run[16];
        float16v o_acc[2] = {};
#pragma unroll
        for (int r = 0; r < 16; r++) { m_run[r] = -1e30f; l_run[r] = 0.f; }

        const int nkt = 2 * qt + 2;
        for (int kt = 0; kt < nkt; kt++) {
            const int kb = kt * 64;
            __syncthreads();
            *(short8*)&Ks[srow * 72 + scc]        = *(const short8*)&Kg[(kb + srow) * 64 + scc];
            *(short8*)&Ks[(srow + 32) * 72 + scc] = *(const short8*)&Kg[(kb + srow + 32) * 64 + scc];
            *(short8*)&Vs[srow * 72 + scc]        = *(const short8*)&Vg[(size_t)srow * S + kb + scc];
            *(short8*)&Vs[(srow + 32) * 72 + scc] = *(const short8*)&Vg[(size_t)(srow + 32) * S + kb + scc];
            __syncthreads();
            if (kb > wbase) continue;   // wave-uniform: tile entirely above this wave's diagonal

            float16v sacc[2] = {};
#pragma unroll
            for (int kst = 0; kst < 4; kst++) {
                bf16x8 bk0 = *(const bf16x8*)&Ks[n32 * 72 + kst * 16 + khalf * 8];
                bf16x8 bk1 = *(const bf16x8*)&Ks[(32 + n32) * 72 + kst * 16 + khalf * 8];
                sacc[0] = __builtin_amdgcn_mfma_f32_32x32x16_bf16(aq[kst], bk0, sacc[0], 0, 0, 0);
                sacc[1] = __builtin_amdgcn_mfma_f32_32x32x16_bf16(aq[kst], bk1, sacc[1], 0, 0, 0);
            }
            const bool domask = (kb + 63 > wbase);
#pragma unroll
            for (int r = 0; r < 16; r++) {
                float s0 = sacc[0][r] * SC2, s1 = sacc[1][r] * SC2;
                int prow = (r & 3) + 8 * (r >> 2) + 4 * khalf;
                if (domask) {
                    int qrow = wbase + prow;
                    if (kb + n32 > qrow)      s0 = -1e30f;
                    if (kb + 32 + n32 > qrow) s1 = -1e30f;
                }
                float mx = fmaxf(s0, s1);
#pragma unroll
                for (int off = 1; off < 32; off <<= 1) mx = fmaxf(mx, __shfl_xor(mx, off));
                float mnew = fmaxf(m_run[r], mx);
                float alpha = __builtin_amdgcn_exp2f(m_run[r] - mnew);
                float p0 = __builtin_amdgcn_exp2f(s0 - mnew);
                float p1 = __builtin_amdgcn_exp2f(s1 - mnew);
                float rsum = p0 + p1;
#pragma unroll
                for (int off = 1; off < 32; off <<= 1) rsum += __shfl_xor(rsum, off);
                m_run[r] = mnew;
                l_run[r] = l_run[r] * alpha + rsum;
                o_acc[0][r] *= alpha;
                o_acc[1][r] *= alpha;
                Pw[prow * 72 + n32]      = f2b(p0);
                Pw[prow * 72 + 32 + n32] = f2b(p1);
            }
            // PV (Pw wave-private: no barrier)
#pragma unroll
            for (int kst = 0; kst < 4; kst++) {
                bf16x8 ap  = *(const bf16x8*)&Pw[n32 * 72 + kst * 16 + khalf * 8];
                bf16x8 bv0 = *(const bf16x8*)&Vs[n32 * 72 + kst * 16 + khalf * 8];
                bf16x8 bv1 = *(const bf16x8*)&Vs[(32 + n32) * 72 + kst * 16 + khalf * 8];
                o_acc[0] = __builtin_amdgcn_mfma_f32_32x32x16_bf16(ap, bv0, o_acc[0], 0, 0, 0);
                o_acc[1] = __builtin_amdgcn_mfma_f32_32x32x16_bf16(ap, bv1, o_acc[1], 0, 0, 0);
            }
        }
        // epilogue
        const size_t hcol = (size_t)(h & 63) * 64;
#pragma unroll
        for (int r = 0; r < 16; r++) {
            float inv = 1.f / l_run[r];
            int grow = b * S + wbase + (r & 3) + 8 * (r >> 2) + 4 * khalf;
            size_t off = (size_t)grow * H + hcol;
            out[off + n32]      = f2b(o_acc[0][r] * inv);
            out[off + 32 + n32] = f2b(o_acc[1][r] * inv);
        }
    }
}

extern "C" void kernel_launch(void* const* d_in, const int* in_sizes, int n_in,
                              void* d_out, int out_size, void* d_ws, size_t ws_size,
                              hipStream_t stream) {
    const float* hs   = (const float*)d_in[0];
    // d_in[1] alibi, d_in[2] attention_mask: unused by reference (zeros)
    const float* cosb = (const float*)d_in[3];
    const float* sinb = (const float*)d_in[4];
    const float* wq   = (const float*)d_in[5];
    const float* wk   = (const float*)d_in[6];
    const float* wv   = (const float*)d_in[7];
    const float* wd   = (const float*)d_in[8];

    char* p = (char*)d_ws;
    auto alloc = [&](size_t bytes) { char* r = p; p += (bytes + 255) & ~(size_t)255; return r; };
    unsigned short* wqkv_b = (unsigned short*)alloc((size_t)NQKV * H * 2);
    unsigned short* wd_b   = (unsigned short*)alloc((size_t)H * H * 2);
    unsigned short* qa     = (unsigned short*)alloc((size_t)BB * NH * S * D * 2);
    unsigned short* ka     = (unsigned short*)alloc((size_t)BB * NKV * S * D * 2);
    unsigned short* vt     = (unsigned short*)alloc((size_t)BB * NKV * S * D * 2);
    unsigned short* hs_b   = (unsigned short*)alloc((size_t)MROWS * H * 2);
    unsigned short* ao     = hs_b;  // alias: hs_b consumed by gemm_qkv before attn writes ao

    cvt_all<<<4096, 256, 0, stream>>>(hs, wq, wk, wv, wd, hs_b, wqkv_b, wd_b);
    gemm_qkv<<<dim3(NQKV / 128, MROWS / 128), 256, 0, stream>>>(hs_b, wqkv_b, cosb, sinb, qa, ka, vt);
    attn_kernel<<<dim3(4, 128), 256, 0, stream>>>(qa, ka, vt, ao);
    gemm_nt_f32<<<dim3(H / 128, MROWS / 128), 256, 0, stream>>>(ao, wd_b, (float*)d_out, MROWS, H, H);
}